// Round 7
// baseline (304.272 us; speedup 1.0000x reference)
//
#include <hip/hip_runtime.h>
#include <hip/hip_bf16.h>
#include <stdint.h>

// B=2, H=16, S=2048, D=64, dropout p=0.1, key = jax.random.key(42)
// JAX partitionable threefry: bits(f) = y0^y1, (y0,y1)=threefry2x32(key,(0,f))
typedef __attribute__((ext_vector_type(8))) short short8;
typedef __attribute__((ext_vector_type(4))) float f32x4;
typedef __attribute__((ext_vector_type(4))) uint32_t u32x4;
typedef __attribute__((ext_vector_type(2))) uint32_t u32x2;

#define KEEP_TH 0xE6666600u  // bits < TH  <=>  jax uniform(bits) < float32(0.9)

// ws layout (floats): acc parts [p][b][h][s][d] = 2*2*16*2048*64 = 8388608,
// then lsum parts [p][b][h][s] = 2*65536 = 131072. Total 8519680 f = 34078720 B.
#define WS_ACC_PART 4194304
#define WS_L_BASE   8388608
#define WS_L_PART   65536
#define WS_NEED_BYTES 34078720ull

// 2x f32 -> packed bf16 pair in ONE op (RNE). No builtin on gfx950; inline asm.
__device__ __forceinline__ uint32_t pkbf(float lo, float hi) {
  uint32_t r;
  asm("v_cvt_pk_bf16_f32 %0, %1, %2" : "=v"(r) : "v"(lo), "v"(hi));
  return r;
}

// threefry2x32 with key (0,42), counter (0, f), x1pre = f + 42 already added.
// ks = [0, 42, 0x1BD11BF0]. Returns y0 ^ y1.
__device__ __forceinline__ uint32_t tf_bits(uint32_t x1pre) {
  uint32_t x1 = x1pre;
  uint32_t x0 = x1;                                   // round 1: x0 = 0 + x1
  x1 = __builtin_rotateleft32(x1, 13) ^ x0;
#define R(r) { x0 += x1; x1 = __builtin_rotateleft32(x1, (r)) ^ x0; }
  R(15) R(26) R(6)
  x0 += 42u;          x1 += 0x1BD11BF0u + 1u;
  R(17) R(29) R(16) R(24)
  x0 += 0x1BD11BF0u;  x1 += 2u;
  R(13) R(15) R(26) R(6)
                      x1 += 42u + 3u;
  R(17) R(29) R(16) R(24)
  x0 += 42u;          x1 += 0x1BD11BF0u + 4u;
  R(13) R(15) R(26) R(6)
  x0 += 0x1BD11BF0u;  x1 += 5u;
#undef R
  return x0 ^ x1;
}

// LDS layout: flat arrays of 512 x 16B "entries" (4 u32 = 8 bf16 along K).
//  K  entry (Tk,kc,g,e) = ((Tk*2+kc)*4+g)*16+e : K[key=Tk*16+e][d=kc*32+8g..+7]
//  V  entry (dt,gk,e)   = (dt*8+gk)*16+e       : V[key=8gk..8gk+7][d=dt*16+e]
//  P  entry (w,gp,e)    = (w*8+gp)*16+e        : P[query=e][key=8gp..8gp+7]
// All fragment reads/writes are 64 consecutive entries per wave -> conflict-free.

__global__ __launch_bounds__(256, 6)
void attn_main(const float* __restrict__ Qg, const float* __restrict__ Kg,
               const float* __restrict__ Vg, const float* __restrict__ invs,
               float* __restrict__ Out, float* __restrict__ Ws, int split) {
  __shared__ __align__(16) uint32_t KbF[512 * 4];
  __shared__ __align__(16) uint32_t VtF[512 * 4];
  __shared__ __align__(16) uint32_t PlF[512 * 4];

  const int tid = threadIdx.x;
  const int w = tid >> 6;
  const int l = tid & 63;
  const int e = l & 15;
  const int g = l >> 4;

  // block decode with XCD affinity on low bits; t-half from bit 10 (split mode)
  const int n  = blockIdx.x;
  const int m  = n & 1023;
  const int half = split ? (n >> 10) : 0;
  const int bh = (m & 7) * 4 + ((m >> 3) & 3);   // 0..31
  const int b  = bh >> 4;
  const int h  = bh & 15;
  const int qc = m >> 5;                         // 0..31
  const int qbase = qc * 64;
  const int tile_lo  = half * 16;
  const int tile_cnt = split ? 16 : 32;

  const float c = 1.4426950408889634f / invs[0]; // log2(e)/inv_scale, folded into Q
  const int sq = qbase + w * 16 + e;             // this lane's query row

  // Q fragments (B operand: n-line = query e, k = d = kc*32 + 8g + j), pre-scaled by c
  short8 qf[2];
#pragma unroll
  for (int kc = 0; kc < 2; ++kc) {
    const float* qp = Qg + (((b * 2048 + sq) * 16 + h) * 64 + kc * 32 + 8 * g);
    f32x4 q0 = *(const f32x4*)qp;
    f32x4 q1 = *(const f32x4*)(qp + 4);
    u32x4 u;
    u.x = pkbf(q0.x * c, q0.y * c);
    u.y = pkbf(q0.z * c, q0.w * c);
    u.z = pkbf(q1.x * c, q1.y * c);
    u.w = pkbf(q1.z * c, q1.w * c);
    qf[kc] = __builtin_bit_cast(short8, u);
  }

  f32x4 acc[4];
#pragma unroll
  for (int dt = 0; dt < 4; ++dt) acc[dt] = (f32x4){0.f, 0.f, 0.f, 0.f};
  float ls[4] = {0.f, 0.f, 0.f, 0.f};

  // mask flat index: f = b*2^26 + h*2^22 + s*2^11 + t
  const uint32_t fb = ((uint32_t)b << 26) | ((uint32_t)h << 22) | ((uint32_t)sq << 11);

  // staging roles
  const int s_e = tid & 15, s_g = (tid >> 4) & 3, s_kc = (tid >> 6) & 1, s_T = tid >> 7;
  const int v_e = tid & 15, v_gk = (tid >> 4) & 7, v_dt = tid >> 7;

  const float* kbase = Kg + (((b * 2048 + s_T * 16 + s_e) * 16 + h) * 64 + s_kc * 32 + 8 * s_g);
  const float* vbase = Vg + (((b * 2048 + 8 * v_gk) * 16 + h) * 64 + v_dt * 16 + v_e);

  // prefetch registers (T14 async-stage split)
  f32x4 kA[2], kB[2];
  float vR[2][8];

  auto prefetch = [&](int tile) {
    const int tt = tile * 64;
#pragma unroll
    for (int r2 = 0; r2 < 2; ++r2) {
      const float* p = kbase + (tt + r2 * 32) * 1024;
      kA[r2] = *(const f32x4*)p;
      kB[r2] = *(const f32x4*)(p + 4);
      const float* pv = vbase + tt * 1024 + r2 * 32;
#pragma unroll
      for (int r = 0; r < 8; ++r) vR[r2][r] = pv[r * 1024];
    }
  };

  prefetch(tile_lo);

  for (int tile = tile_lo; tile < tile_lo + tile_cnt; ++tile) {
    const int t0 = tile * 64;
    __syncthreads();   // prev tile's LDS reads done before overwrite

    // ---- store prefetched tile into LDS (cvt_pk + linear b128 writes) ----
#pragma unroll
    for (int r2 = 0; r2 < 2; ++r2) {
      int Tk = s_T + 2 * r2;
      u32x4 u;
      u.x = pkbf(kA[r2].x, kA[r2].y);
      u.y = pkbf(kA[r2].z, kA[r2].w);
      u.z = pkbf(kB[r2].x, kB[r2].y);
      u.w = pkbf(kB[r2].z, kB[r2].w);
      *(u32x4*)&KbF[(((Tk * 2 + s_kc) * 4 + s_g) * 16 + s_e) * 4] = u;

      int dt = v_dt + 2 * r2;
      u32x4 uv;
      uv.x = pkbf(vR[r2][0], vR[r2][1]);
      uv.y = pkbf(vR[r2][2], vR[r2][3]);
      uv.z = pkbf(vR[r2][4], vR[r2][5]);
      uv.w = pkbf(vR[r2][6], vR[r2][7]);
      *(u32x4*)&VtF[((dt * 8 + v_gk) * 16 + v_e) * 4] = uv;
    }
    __syncthreads();

    // ---- issue next tile's global loads (latency hides under compute) ----
    if (tile + 1 < tile_lo + tile_cnt) prefetch(tile + 1);

    // ---- QK^T + softmax numerator + dropout mask ----
#pragma unroll
    for (int Tk = 0; Tk < 4; ++Tk) {
      u32x4 ku0 = *(const u32x4*)&KbF[(((Tk * 2 + 0) * 4 + g) * 16 + e) * 4];
      u32x4 ku1 = *(const u32x4*)&KbF[(((Tk * 2 + 1) * 4 + g) * 16 + e) * 4];
      f32x4 sacc = (f32x4){0.f, 0.f, 0.f, 0.f};
      sacc = __builtin_amdgcn_mfma_f32_16x16x32_bf16(__builtin_bit_cast(short8, ku0), qf[0], sacc, 0, 0, 0);
      sacc = __builtin_amdgcn_mfma_f32_16x16x32_bf16(__builtin_bit_cast(short8, ku1), qf[1], sacc, 0, 0, 0);
      const uint32_t jT = fb + (uint32_t)(t0 + 16 * Tk + 4 * g + 42);
      float pm[4];
#pragma unroll
      for (int r = 0; r < 4; ++r) {
        uint32_t bits = tf_bits(jT + (uint32_t)r);
        float pv = __builtin_amdgcn_exp2f(sacc[r]);
        ls[r] += pv;                        // denominator is pre-dropout
        pm[r] = (bits < KEEP_TH) ? pv : 0.f;
      }
      int gp = 2 * Tk + (g >> 1);
      u32x2 pw;
      pw.x = pkbf(pm[0], pm[1]);
      pw.y = pkbf(pm[2], pm[3]);
      *(u32x2*)&PlF[((w * 8 + gp) * 16 + e) * 4 + 2 * (g & 1)] = pw;
    }
    asm volatile("" ::: "memory");  // same-wave DS ops are in-order; pin compiler order

    // ---- PV ----
#pragma unroll
    for (int kk = 0; kk < 2; ++kk) {
      u32x4 pu = *(const u32x4*)&PlF[((w * 8 + g + 4 * kk) * 16 + e) * 4];
      short8 pf = __builtin_bit_cast(short8, pu);
#pragma unroll
      for (int dt = 0; dt < 4; ++dt) {
        u32x4 vu = *(const u32x4*)&VtF[((dt * 8 + g + 4 * kk) * 16 + e) * 4];
        acc[dt] = __builtin_amdgcn_mfma_f32_16x16x32_bf16(pf, __builtin_bit_cast(short8, vu), acc[dt], 0, 0, 0);
      }
    }
  }

  // ---- epilogue ----
  float L = (ls[0] + ls[1]) + (ls[2] + ls[3]);
  L += __shfl_xor(L, 16);
  L += __shfl_xor(L, 32);               // full partial row-sum for query e in all lanes

  if (split) {
    // dump unnormalized partials to workspace
    const int pbase = (half * 32 + b * 16 + h) * 2048;
#pragma unroll
    for (int dt = 0; dt < 4; ++dt)
#pragma unroll
      for (int r = 0; r < 4; ++r) {
        int s = qbase + w * 16 + 4 * g + r;
        Ws[(pbase + s) * 64 + dt * 16 + e] = acc[dt][r];
      }
    if (l < 16) Ws[WS_L_BASE + half * WS_L_PART + (b * 16 + h) * 2048 + qbase + w * 16 + l] = L;
  } else {
    float rinv = 1.0f / (0.9f * L);
    float rr[4];
#pragma unroll
    for (int r = 0; r < 4; ++r) rr[r] = __shfl(rinv, 4 * g + r);
#pragma unroll
    for (int dt = 0; dt < 4; ++dt)
#pragma unroll
      for (int r = 0; r < 4; ++r) {
        int s = qbase + w * 16 + 4 * g + r;
        Out[(((b * 16 + h) * 2048 + s) * 64) + dt * 16 + e] = acc[dt][r] * rr[r];
      }
  }
}

__global__ __launch_bounds__(256)
void attn_combine(const float* __restrict__ Ws, float* __restrict__ Out) {
  const int i4 = blockIdx.x * 256 + threadIdx.x;   // 0..1048575
  const int elem = i4 * 4;
  const int row = elem >> 6;                        // (b*16+h)*2048 + s
  f32x4 a0 = *(const f32x4*)&Ws[elem];
  f32x4 a1 = *(const f32x4*)&Ws[WS_ACC_PART + elem];
  float L = Ws[WS_L_BASE + row] + Ws[WS_L_BASE + WS_L_PART + row];
  float rinv = 1.0f / (0.9f * L);
  f32x4 o;
  o.x = (a0.x + a1.x) * rinv;
  o.y = (a0.y + a1.y) * rinv;
  o.z = (a0.z + a1.z) * rinv;
  o.w = (a0.w + a1.w) * rinv;
  *(f32x4*)&Out[elem] = o;
}

extern "C" void kernel_launch(void* const* d_in, const int* in_sizes, int n_in,
                              void* d_out, int out_size, void* d_ws, size_t ws_size,
                              hipStream_t stream) {
  const float* q  = (const float*)d_in[0];
  const float* k  = (const float*)d_in[1];
  const float* v  = (const float*)d_in[2];
  const float* sc = (const float*)d_in[3];
  float* out = (float*)d_out;
  float* ws  = (float*)d_ws;
  (void)in_sizes; (void)n_in; (void)out_size;

  if (ws_size >= WS_NEED_BYTES) {
    attn_main<<<dim3(2048), dim3(256), 0, stream>>>(q, k, v, sc, out, ws, 1);
    attn_combine<<<dim3(4096), dim3(256), 0, stream>>>(ws, out);
  } else {
    attn_main<<<dim3(1024), dim3(256), 0, stream>>>(q, k, v, sc, out, ws, 0);
  }
}